// Round 8
// baseline (243.976 us; speedup 1.0000x reference)
//
#include <hip/hip_runtime.h>
#include <hip/hip_bf16.h>

// Problem constants: B=8, S=1024, D=768, H=12, DH=64
#define BB 8
#define SS 1024
#define DD 768
#define HH 12
#define LOG2E 1.4426950408889634f

typedef __attribute__((ext_vector_type(8))) _Float16 f16x8;
typedef __attribute__((ext_vector_type(4))) _Float16 f16x4;
typedef __attribute__((ext_vector_type(4))) float f32x4;

typedef __attribute__((address_space(3))) void lds_void;
typedef const __attribute__((address_space(1))) void gmem_void;
#define GLOAD_LDS16(src, dst) \
    __builtin_amdgcn_global_load_lds((gmem_void*)(src), (lds_void*)(dst), 16, 0, 0)

// ---------------------------------------------------------------------------
// Kernel 1: fp32 -> fp16 convert of X and W (concat Wq|Wk|Wv), bias concat,
//   click pre-scaled by 0.125*log2e and mask by log2e (exp2-domain softmax).
// ---------------------------------------------------------------------------
__global__ void prep_kernel(const float* __restrict__ X,
                            const float* __restrict__ Wq,
                            const float* __restrict__ Wk,
                            const float* __restrict__ Wv,
                            const float* __restrict__ bq,
                            const float* __restrict__ bk,
                            const float* __restrict__ bv,
                            const float* __restrict__ click,
                            const float* __restrict__ mask,
                            _Float16* __restrict__ Xh,
                            _Float16* __restrict__ Wh,
                            float* __restrict__ bias,
                            float* __restrict__ ckS,
                            float* __restrict__ mkL) {
    const int NX4 = (BB * SS * DD) / 4;   // 1572864
    const int NW4 = (DD * DD) / 4;        // 147456
    const int tid = blockIdx.x * blockDim.x + threadIdx.x;
    const int nth = gridDim.x * blockDim.x;

    for (int i = tid; i < NX4; i += nth) {
        f32x4 x = ((const f32x4*)X)[i];
        f16x4 h;
        for (int j = 0; j < 4; ++j) h[j] = (_Float16)x[j];
        ((f16x4*)Xh)[i] = h;
    }
    for (int i = tid; i < 3 * NW4; i += nth) {
        const float* src = (i < NW4) ? Wq : (i < 2 * NW4 ? Wk : Wv);
        const int ii = (i < NW4) ? i : (i < 2 * NW4 ? i - NW4 : i - 2 * NW4);
        f32x4 x = ((const f32x4*)src)[ii];
        f16x4 h;
        for (int j = 0; j < 4; ++j) h[j] = (_Float16)x[j];
        ((f16x4*)Wh)[i] = h;
    }
    for (int i = tid; i < 3 * DD; i += nth) {
        bias[i] = (i < DD) ? bq[i] : (i < 2 * DD ? bk[i - DD] : bv[i - 2 * DD]);
    }
    for (int i = tid; i < BB * SS; i += nth) {
        ckS[i] = (0.125f * LOG2E) * click[i];
        mkL[i] = LOG2E * mask[i];
    }
}

// ---------------------------------------------------------------------------
// Kernel 2: fused QKV GEMM, 128x192 block tile, BK=32, 4 waves (wave 64x96).
//   Grid 768 = exactly 3/CU; XCD-swizzled; global_load_lds + source
//   pre-swizzle (rule #21).  [unchanged from R4]
// ---------------------------------------------------------------------------
__global__ __launch_bounds__(256, 3) void qkv_gemm(const _Float16* __restrict__ Xh,
                                                   const _Float16* __restrict__ Wh,
                                                   const float* __restrict__ bias,
                                                   _Float16* __restrict__ Qb,
                                                   _Float16* __restrict__ Kb,
                                                   _Float16* __restrict__ Vt) {
    __shared__ __align__(16) _Float16 At[2][128 * 32];
    __shared__ __align__(16) _Float16 Bt[2][192 * 32];

    const int tid = threadIdx.x;
    const int l = tid & 63, w = tid >> 6;
    const int wm = w >> 1, wn = w & 1;

    const int bid = blockIdx.x;
    const int nid = (bid & 7) * 96 + (bid >> 3);
    const int bx = nid / 12;
    const int by = nid - bx * 12;
    const int mblk = bx * 128, nblk = by * 192;

    const int lr = l & 15, lg = l >> 4;
    const int mbase = mblk + wm * 64, nbase = nblk + wn * 96;

    const int sr_i = l >> 2;
    const int scb  = (l & 3) << 4;
    const int sx   = (sr_i >> 1) & 3;
    const int scol = (scb ^ (sx << 4)) >> 1;

    const _Float16* Ag = Xh + (size_t)(mblk + w * 32 + sr_i) * DD + scol;
    const _Float16* Bg = Wh + (size_t)(nblk + w * 48 + sr_i) * DD + scol;

    const int ax = (lr >> 1) & 3;
    const int acol = (lg ^ ax) << 3;
    const int arow0 = (wm * 64 + lr) * 32 + acol;
    const int brow0 = (wn * 96 + lr) * 32 + acol;

    f32x4 acc[4][6] = {};

#pragma unroll
    for (int i = 0; i < 2; ++i)
        GLOAD_LDS16(Ag + i * 16 * DD, &At[0][w * 1024 + i * 512]);
#pragma unroll
    for (int i = 0; i < 3; ++i)
        GLOAD_LDS16(Bg + i * 16 * DD, &Bt[0][w * 1536 + i * 512]);
    __syncthreads();

    for (int s_ = 0; s_ < 24; ++s_) {
        const int cur = s_ & 1;
        if (s_ < 23) {
            const int kk = (s_ + 1) * 32;
#pragma unroll
            for (int i = 0; i < 2; ++i)
                GLOAD_LDS16(Ag + kk + i * 16 * DD, &At[cur ^ 1][w * 1024 + i * 512]);
#pragma unroll
            for (int i = 0; i < 3; ++i)
                GLOAD_LDS16(Bg + kk + i * 16 * DD, &Bt[cur ^ 1][w * 1536 + i * 512]);
        }
        f16x8 a[4];
#pragma unroll
        for (int mi = 0; mi < 4; ++mi)
            a[mi] = *(const f16x8*)(&At[cur][arow0 + mi * 512]);
        __builtin_amdgcn_s_setprio(1);
#pragma unroll
        for (int ni = 0; ni < 6; ++ni) {
            const f16x8 b = *(const f16x8*)(&Bt[cur][brow0 + ni * 512]);
#pragma unroll
            for (int mi = 0; mi < 4; ++mi)
                acc[mi][ni] = __builtin_amdgcn_mfma_f32_16x16x32_f16(
                    a[mi], b, acc[mi][ni], 0, 0, 0);
        }
        __builtin_amdgcn_s_setprio(0);
        __syncthreads();
    }

#pragma unroll
    for (int ni = 0; ni < 6; ++ni) {
        const int n = nbase + ni * 16 + lr;
        const float bv_ = bias[n];
        const int proj = (n >= 2 * DD) ? 2 : (n >= DD ? 1 : 0);
        const int rem = n - proj * DD;
        const int h = rem >> 6, dh = rem & 63;
#pragma unroll
        for (int mi = 0; mi < 4; ++mi) {
            const int m0 = mbase + mi * 16 + lg * 4;
            const int b_ = m0 >> 10;
            const int s0 = m0 & 1023;
            const int bh = b_ * HH + h;
            f32x4 v = acc[mi][ni];
            if (proj == 2) {
                f16x4 pk;
#pragma unroll
                for (int r = 0; r < 4; ++r) pk[r] = (_Float16)(v[r] + bv_);
                *(f16x4*)(Vt + ((size_t)bh * 64 + dh) * SS + s0) = pk;
            } else {
                _Float16* dst = (proj == 0) ? Qb : Kb;
#pragma unroll
                for (int r = 0; r < 4; ++r)
                    dst[((size_t)bh * SS + (s0 + r)) * 64 + dh] =
                        (_Float16)(v[r] + bv_);
            }
        }
    }
}

// ---------------------------------------------------------------------------
// Kernel 3: flash attention, 8 waves/block (512 thr), 16 q-rows per wave.
//   [R7 changes] (1) 8-wave blocks: 24 waves/CU resident (75% nominal occ,
//   3x the measured 25%); per-wave state halves -> fits 85-VGPR cap of
//   __launch_bounds__(512,6).  (2) V staging dropped: V frags read directly
//   from global (L2-resident via XCD swizzle; m169 precedent) -> LDS 26 KB.
//   (3) Cross-lane max shfls gated behind the rare defer-max branch.
// ---------------------------------------------------------------------------
__global__ __launch_bounds__(512, 6) void attn_kernel(const _Float16* __restrict__ Qb,
                                                      const _Float16* __restrict__ Kb,
                                                      const _Float16* __restrict__ Vt,
                                                      const float* __restrict__ ckS,
                                                      const float* __restrict__ mkL,
                                                      float* __restrict__ out) {
    __shared__ __align__(16) _Float16 Ksh[2][64 * 64];
    __shared__ __align__(16) _Float16 pT[8][16][40];

    const int tid = threadIdx.x;
    const int l = tid & 63, w = tid >> 6;    // w = 0..7
    const int lr = l & 15, lg = l >> 4;

    // XCD swizzle: 768 blocks, 96 per XCD -> 12 bh per XCD (K+V 3MB in L2)
    const int bid = blockIdx.x;
    const int nid = (bid & 7) * 96 + (bid >> 3);
    const int qt2 = nid & 7;
    const int bh  = nid >> 3;
    const int b_ = bh / HH, h = bh - b_ * HH;
    const int qbase = qt2 * 128 + w * 16;

    const _Float16* Qp = Qb + (size_t)bh * (SS * 64);
    const _Float16* Kp = Kb + (size_t)bh * (SS * 64);
    const _Float16* Vp = Vt + (size_t)bh * (SS * 64);
    const float* ck = ckS + b_ * SS;
    const float* mk = mkL + b_ * SS;

    const f16x8 qf0 = *(const f16x8*)(Qp + (size_t)(qbase + lr) * 64 + lg * 8);
    const f16x8 qf1 = *(const f16x8*)(Qp + (size_t)(qbase + lr) * 64 + 32 + lg * 8);

    // K staging: 512 threads cover the full 64x64 tile in ONE issue.
    //   thread (w,l): row = w*8 + (l>>3), phys byte col (l&7)*16,
    //   source pre-swizzled by (row&7)<<4 = (l>>3)<<4 (rule #21).
    const int srow = l >> 3;
    const int scol = ((((l & 7) << 4) ^ (srow << 4)) >> 1);
    const _Float16* Kg = Kp + (size_t)(w * 8 + srow) * 64 + scol;

    GLOAD_LDS16(Kg, &Ksh[0][w * 512]);
    __syncthreads();

    f32x4 o[4] = {};
    float m_run = -3.0e38f, l_run = 0.f;
    const int sw = (lr & 7) << 4;

    for (int c = 0; c < 16; ++c) {
        const int cur = c & 1;
        if (c < 15)
            GLOAD_LDS16(Kg + (size_t)(c + 1) * 64 * 64, &Ksh[cur ^ 1][w * 512]);
        const _Float16* Ks = Ksh[cur];
        const int cb64 = c * 64;

#pragma unroll
        for (int ks = 0; ks < 2; ++ks) {
            // --- QK^T (swapped): st[t] reg r = S[key=ks*32+t*16+lg*4+r][q=lr]
            f32x4 st[2];
            __builtin_amdgcn_s_setprio(1);
#pragma unroll
            for (int t = 0; t < 2; ++t) {
                const int row = (ks * 2 + t) * 16 + lr;
                const f16x8 kf0 = *(const f16x8*)(Ks + row * 64 + (((lg << 4) ^ sw) >> 1));
                const f16x8 kf1 = *(const f16x8*)(Ks + row * 64 + (((64 | (lg << 4)) ^ sw) >> 1));
                f32x4 z = {};
                z = __builtin_amdgcn_mfma_f32_16x16x32_f16(kf0, qf0, z, 0, 0, 0);
                st[t] = __builtin_amdgcn_mfma_f32_16x16x32_f16(kf1, qf1, z, 0, 0, 0);
            }
            __builtin_amdgcn_s_setprio(0);

            const int koff = cb64 + ks * 32 + lg * 4;
            const f32x4 ck0 = *(const f32x4*)(ck + koff);
            const f32x4 ck1 = *(const f32x4*)(ck + koff + 16);
            const f32x4 mk0 = *(const f32x4*)(mk + koff);
            const f32x4 mk1 = *(const f32x4*)(mk + koff + 16);

            // scores in log2 domain
            float s0[4], s1[4];
#pragma unroll
            for (int r = 0; r < 4; ++r) {
                s0[r] = st[0][r] * ck0[r] + mk0[r];
                s1[r] = st[1][r] * ck1[r] + mk1[r];
            }
            const float lmax =
                fmaxf(fmaxf(fmaxf(s0[0], s0[1]), fmaxf(s0[2], s0[3])),
                      fmaxf(fmaxf(s1[0], s1[1]), fmaxf(s1[2], s1[3])));

            // defer-max: cross-lane reduce + rescale only when needed
            // (threshold 8*log2e in log2 domain -> P bounded by e^8)
            if (__any(lmax - m_run > 11.5415603f)) {
                float tmax = lmax;
                tmax = fmaxf(tmax, __shfl_xor(tmax, 16));
                tmax = fmaxf(tmax, __shfl_xor(tmax, 32));
                const float m_new = fmaxf(m_run, tmax);
                const float sc = __builtin_amdgcn_exp2f(m_run - m_new);
                l_run *= sc;
#pragma unroll
                for (int f = 0; f < 4; ++f)
#pragma unroll
                    for (int r = 0; r < 4; ++r) o[f][r] *= sc;
                m_run = m_new;
            }

            float psum = 0.f;
            f16x4 pk0, pk1;
#pragma unroll
            for (int r = 0; r < 4; ++r) {
                const float p0 = __builtin_amdgcn_exp2f(s0[r] - m_run);
                const float p1 = __builtin_amdgcn_exp2f(s1[r] - m_run);
                psum += p0 + p1;
                pk0[r] = (_Float16)p0;
                pk1[r] = (_Float16)p1;
            }
            l_run += psum;       // per-lane partial; reduced in epilogue

            // --- P^T bounce (wave-private)
            *(f16x4*)(&pT[w][lr][lg * 4]) = pk0;
            *(f16x4*)(&pT[w][lr][16 + lg * 4]) = pk1;
            const f16x8 pb = *(const f16x8*)(&pT[w][lr][lg * 8]);

            // --- PV: V frags direct from global (L2-resident)
            __builtin_amdgcn_s_setprio(1);
#pragma unroll
            for (int f = 0; f < 4; ++f) {
                const f16x8 vf = *(const f16x8*)(Vp + (size_t)(f * 16 + lr) * SS +
                                                 cb64 + ks * 32 + lg * 8);
                o[f] = __builtin_amdgcn_mfma_f32_16x16x32_f16(vf, pb, o[f], 0, 0, 0);
            }
            __builtin_amdgcn_s_setprio(0);
        }
        __syncthreads();   // drain next-K staging + release Ksh[cur]
    }

    // --- epilogue: cross-lane l_run reduction (once), normalize + store
    float lt = l_run;
    lt += __shfl_xor(lt, 16);
    lt += __shfl_xor(lt, 32);
    const float inv = 1.f / lt;
#pragma unroll
    for (int f = 0; f < 4; ++f) {
        f32x4 v = o[f];
#pragma unroll
        for (int r = 0; r < 4; ++r) v[r] *= inv;
        float* dst = out + ((size_t)(b_ * SS + qbase + lr)) * DD +
                     h * 64 + f * 16 + lg * 4;
        *(f32x4*)dst = v;
    }
}

// ---------------------------------------------------------------------------
// Launch
// ---------------------------------------------------------------------------
extern "C" void kernel_launch(void* const* d_in, const int* in_sizes, int n_in,
                              void* d_out, int out_size, void* d_ws, size_t ws_size,
                              hipStream_t stream) {
    const float* X     = (const float*)d_in[0];
    const float* mask  = (const float*)d_in[1];
    const float* click = (const float*)d_in[2];
    const float* Wq    = (const float*)d_in[3];
    const float* bq    = (const float*)d_in[4];
    const float* Wk    = (const float*)d_in[5];
    const float* bk    = (const float*)d_in[6];
    const float* Wv    = (const float*)d_in[7];
    const float* bv    = (const float*)d_in[8];
    float* out = (float*)d_out;

    char* ws = (char*)d_ws;
    _Float16* Xh  = (_Float16*)(ws);                  // 12,582,912 B
    _Float16* Wh  = (_Float16*)(ws + 12582912);       //  3,538,944 B
    float*    bia = (float*)   (ws + 16121856);       //      9,216 B
    float*    ckS = (float*)   (ws + 16131072);       //     32,768 B
    float*    mkL = (float*)   (ws + 16163840);       //     32,768 B
    _Float16* Qb  = (_Float16*)(ws + 16196608);       // 12,582,912 B
    _Float16* Kb  = (_Float16*)(ws + 28779520);       // 12,582,912 B
    _Float16* Vt  = (_Float16*)(ws + 41362432);       // 12,582,912 B

    prep_kernel<<<2048, 256, 0, stream>>>(X, Wq, Wk, Wv, bq, bk, bv, click, mask,
                                          Xh, Wh, bia, ckS, mkL);
    qkv_gemm<<<768, 256, 0, stream>>>(Xh, Wh, bia, Qb, Kb, Vt);
    attn_kernel<<<768, 512, 0, stream>>>(Qb, Kb, Vt, ckS, mkL, out);
}

// Round 12
// 177.873 us; speedup vs baseline: 1.3716x; 1.3716x over previous
//
#include <hip/hip_runtime.h>
#include <hip/hip_bf16.h>

// Problem constants: B=8, S=1024, D=768, H=12, DH=64
#define BB 8
#define SS 1024
#define DD 768
#define HH 12
#define LOG2E 1.4426950408889634f

typedef __attribute__((ext_vector_type(8))) _Float16 f16x8;
typedef __attribute__((ext_vector_type(4))) _Float16 f16x4;
typedef __attribute__((ext_vector_type(4))) float f32x4;

typedef __attribute__((address_space(3))) void lds_void;
typedef const __attribute__((address_space(1))) void gmem_void;
#define GLOAD_LDS16(src, dst) \
    __builtin_amdgcn_global_load_lds((gmem_void*)(src), (lds_void*)(dst), 16, 0, 0)

// ---------------------------------------------------------------------------
// Kernel 1: fp32 -> fp16 convert of X and W (concat Wq|Wk|Wv), bias concat,
//   click pre-scaled by 0.125*log2e and mask by log2e (exp2-domain softmax).
// ---------------------------------------------------------------------------
__global__ void prep_kernel(const float* __restrict__ X,
                            const float* __restrict__ Wq,
                            const float* __restrict__ Wk,
                            const float* __restrict__ Wv,
                            const float* __restrict__ bq,
                            const float* __restrict__ bk,
                            const float* __restrict__ bv,
                            const float* __restrict__ click,
                            const float* __restrict__ mask,
                            _Float16* __restrict__ Xh,
                            _Float16* __restrict__ Wh,
                            float* __restrict__ bias,
                            float* __restrict__ ckS,
                            float* __restrict__ mkL) {
    const int NX4 = (BB * SS * DD) / 4;   // 1572864
    const int NW4 = (DD * DD) / 4;        // 147456
    const int tid = blockIdx.x * blockDim.x + threadIdx.x;
    const int nth = gridDim.x * blockDim.x;

    for (int i = tid; i < NX4; i += nth) {
        f32x4 x = ((const f32x4*)X)[i];
        f16x4 h;
        for (int j = 0; j < 4; ++j) h[j] = (_Float16)x[j];
        ((f16x4*)Xh)[i] = h;
    }
    for (int i = tid; i < 3 * NW4; i += nth) {
        const float* src = (i < NW4) ? Wq : (i < 2 * NW4 ? Wk : Wv);
        const int ii = (i < NW4) ? i : (i < 2 * NW4 ? i - NW4 : i - 2 * NW4);
        f32x4 x = ((const f32x4*)src)[ii];
        f16x4 h;
        for (int j = 0; j < 4; ++j) h[j] = (_Float16)x[j];
        ((f16x4*)Wh)[i] = h;
    }
    for (int i = tid; i < 3 * DD; i += nth) {
        bias[i] = (i < DD) ? bq[i] : (i < 2 * DD ? bk[i - DD] : bv[i - 2 * DD]);
    }
    for (int i = tid; i < BB * SS; i += nth) {
        ckS[i] = (0.125f * LOG2E) * click[i];
        mkL[i] = LOG2E * mask[i];
    }
}

// ---------------------------------------------------------------------------
// Kernel 2: fused QKV GEMM, 128x192 block tile, BK=32, 4 waves (wave 64x96).
//   Grid 768 = exactly 3/CU; XCD-swizzled; global_load_lds + source
//   pre-swizzle (rule #21).  [unchanged from R4]
// ---------------------------------------------------------------------------
__global__ __launch_bounds__(256, 3) void qkv_gemm(const _Float16* __restrict__ Xh,
                                                   const _Float16* __restrict__ Wh,
                                                   const float* __restrict__ bias,
                                                   _Float16* __restrict__ Qb,
                                                   _Float16* __restrict__ Kb,
                                                   _Float16* __restrict__ Vt) {
    __shared__ __align__(16) _Float16 At[2][128 * 32];
    __shared__ __align__(16) _Float16 Bt[2][192 * 32];

    const int tid = threadIdx.x;
    const int l = tid & 63, w = tid >> 6;
    const int wm = w >> 1, wn = w & 1;

    const int bid = blockIdx.x;
    const int nid = (bid & 7) * 96 + (bid >> 3);
    const int bx = nid / 12;
    const int by = nid - bx * 12;
    const int mblk = bx * 128, nblk = by * 192;

    const int lr = l & 15, lg = l >> 4;
    const int mbase = mblk + wm * 64, nbase = nblk + wn * 96;

    const int sr_i = l >> 2;
    const int scb  = (l & 3) << 4;
    const int sx   = (sr_i >> 1) & 3;
    const int scol = (scb ^ (sx << 4)) >> 1;

    const _Float16* Ag = Xh + (size_t)(mblk + w * 32 + sr_i) * DD + scol;
    const _Float16* Bg = Wh + (size_t)(nblk + w * 48 + sr_i) * DD + scol;

    const int ax = (lr >> 1) & 3;
    const int acol = (lg ^ ax) << 3;
    const int arow0 = (wm * 64 + lr) * 32 + acol;
    const int brow0 = (wn * 96 + lr) * 32 + acol;

    f32x4 acc[4][6] = {};

#pragma unroll
    for (int i = 0; i < 2; ++i)
        GLOAD_LDS16(Ag + i * 16 * DD, &At[0][w * 1024 + i * 512]);
#pragma unroll
    for (int i = 0; i < 3; ++i)
        GLOAD_LDS16(Bg + i * 16 * DD, &Bt[0][w * 1536 + i * 512]);
    __syncthreads();

    for (int s_ = 0; s_ < 24; ++s_) {
        const int cur = s_ & 1;
        if (s_ < 23) {
            const int kk = (s_ + 1) * 32;
#pragma unroll
            for (int i = 0; i < 2; ++i)
                GLOAD_LDS16(Ag + kk + i * 16 * DD, &At[cur ^ 1][w * 1024 + i * 512]);
#pragma unroll
            for (int i = 0; i < 3; ++i)
                GLOAD_LDS16(Bg + kk + i * 16 * DD, &Bt[cur ^ 1][w * 1536 + i * 512]);
        }
        f16x8 a[4];
#pragma unroll
        for (int mi = 0; mi < 4; ++mi)
            a[mi] = *(const f16x8*)(&At[cur][arow0 + mi * 512]);
        __builtin_amdgcn_s_setprio(1);
#pragma unroll
        for (int ni = 0; ni < 6; ++ni) {
            const f16x8 b = *(const f16x8*)(&Bt[cur][brow0 + ni * 512]);
#pragma unroll
            for (int mi = 0; mi < 4; ++mi)
                acc[mi][ni] = __builtin_amdgcn_mfma_f32_16x16x32_f16(
                    a[mi], b, acc[mi][ni], 0, 0, 0);
        }
        __builtin_amdgcn_s_setprio(0);
        __syncthreads();
    }

#pragma unroll
    for (int ni = 0; ni < 6; ++ni) {
        const int n = nbase + ni * 16 + lr;
        const float bv_ = bias[n];
        const int proj = (n >= 2 * DD) ? 2 : (n >= DD ? 1 : 0);
        const int rem = n - proj * DD;
        const int h = rem >> 6, dh = rem & 63;
#pragma unroll
        for (int mi = 0; mi < 4; ++mi) {
            const int m0 = mbase + mi * 16 + lg * 4;
            const int b_ = m0 >> 10;
            const int s0 = m0 & 1023;
            const int bh = b_ * HH + h;
            f32x4 v = acc[mi][ni];
            if (proj == 2) {
                f16x4 pk;
#pragma unroll
                for (int r = 0; r < 4; ++r) pk[r] = (_Float16)(v[r] + bv_);
                *(f16x4*)(Vt + ((size_t)bh * 64 + dh) * SS + s0) = pk;
            } else {
                _Float16* dst = (proj == 0) ? Qb : Kb;
#pragma unroll
                for (int r = 0; r < 4; ++r)
                    dst[((size_t)bh * SS + (s0 + r)) * 64 + dh] =
                        (_Float16)(v[r] + bv_);
            }
        }
    }
}

// ---------------------------------------------------------------------------
// Kernel 3: flash attention, 8 waves/block (512 thr), 16 q-rows per wave.
//   [R8] R7 post-mortem: occupancy gain was real (65%) but V-direct-from-
//   global exposed L2 latency on every PV step (125 us).  This version keeps
//   the 8-wave structure AND restores double-buffered LDS V staging (the R5
//   prefetch-a-chunk-ahead pattern).  LDS 42.5 KB -> 3 blocks/CU = 24
//   waves/CU.  Gated cross-lane max + per-lane l_run kept from R7.
// ---------------------------------------------------------------------------
__global__ __launch_bounds__(512, 6) void attn_kernel(const _Float16* __restrict__ Qb,
                                                      const _Float16* __restrict__ Kb,
                                                      const _Float16* __restrict__ Vt,
                                                      const float* __restrict__ ckS,
                                                      const float* __restrict__ mkL,
                                                      float* __restrict__ out) {
    __shared__ __align__(16) _Float16 Ksh[2][64 * 64];
    __shared__ __align__(16) _Float16 Vsh[2][64 * 64];
    __shared__ __align__(16) _Float16 pT[8][16][40];

    const int tid = threadIdx.x;
    const int l = tid & 63, w = tid >> 6;    // w = 0..7
    const int lr = l & 15, lg = l >> 4;

    // XCD swizzle: 768 blocks, 96 per XCD -> 12 bh per XCD (K+V 3MB in L2)
    const int bid = blockIdx.x;
    const int nid = (bid & 7) * 96 + (bid >> 3);
    const int qt2 = nid & 7;
    const int bh  = nid >> 3;
    const int b_ = bh / HH, h = bh - b_ * HH;
    const int qbase = qt2 * 128 + w * 16;

    const _Float16* Qp = Qb + (size_t)bh * (SS * 64);
    const _Float16* Kp = Kb + (size_t)bh * (SS * 64);
    const _Float16* Vp = Vt + (size_t)bh * (SS * 64);
    const float* ck = ckS + b_ * SS;
    const float* mk = mkL + b_ * SS;

    const f16x8 qf0 = *(const f16x8*)(Qp + (size_t)(qbase + lr) * 64 + lg * 8);
    const f16x8 qf1 = *(const f16x8*)(Qp + (size_t)(qbase + lr) * 64 + 32 + lg * 8);

    // Staging: 512 threads cover each 64x64 tile in ONE issue per buffer.
    //   thread (w,l): row = w*8 + (l>>3), phys byte col (l&7)*16,
    //   source pre-swizzled by (row&7)<<4 = ((l>>3))<<4 (rule #21).
    const int srow = l >> 3;                         // 0..7; (w*8+srow)&7 == srow
    const int scol = ((((l & 7) << 4) ^ (srow << 4)) >> 1);
    const _Float16* Kg = Kp + (size_t)(w * 8 + srow) * 64 + scol;   // K: [s][dh]
    const _Float16* Vg = Vp + (size_t)(w * 8 + srow) * SS + scol;   // V^T: [dh][s]

    GLOAD_LDS16(Kg, &Ksh[0][w * 512]);
    GLOAD_LDS16(Vg, &Vsh[0][w * 512]);
    __syncthreads();

    f32x4 o[4] = {};
    float m_run = -3.0e38f, l_run = 0.f;
    const int sw = (lr & 7) << 4;

    for (int c = 0; c < 16; ++c) {
        const int cur = c & 1;
        if (c < 15) {   // prefetch next chunk; in flight under this chunk's compute
            GLOAD_LDS16(Kg + (size_t)(c + 1) * 4096, &Ksh[cur ^ 1][w * 512]);
            GLOAD_LDS16(Vg + (c + 1) * 64,           &Vsh[cur ^ 1][w * 512]);
        }
        const _Float16* Ks = Ksh[cur];
        const _Float16* Vs = Vsh[cur];
        const int cb64 = c * 64;

#pragma unroll
        for (int ks = 0; ks < 2; ++ks) {
            // --- QK^T (swapped): st[t] reg r = S[key=ks*32+t*16+lg*4+r][q=lr]
            f32x4 st[2];
            __builtin_amdgcn_s_setprio(1);
#pragma unroll
            for (int t = 0; t < 2; ++t) {
                const int row = (ks * 2 + t) * 16 + lr;
                const f16x8 kf0 = *(const f16x8*)(Ks + row * 64 + (((lg << 4) ^ sw) >> 1));
                const f16x8 kf1 = *(const f16x8*)(Ks + row * 64 + (((64 | (lg << 4)) ^ sw) >> 1));
                f32x4 z = {};
                z = __builtin_amdgcn_mfma_f32_16x16x32_f16(kf0, qf0, z, 0, 0, 0);
                st[t] = __builtin_amdgcn_mfma_f32_16x16x32_f16(kf1, qf1, z, 0, 0, 0);
            }
            __builtin_amdgcn_s_setprio(0);

            const int koff = cb64 + ks * 32 + lg * 4;
            const f32x4 ck0 = *(const f32x4*)(ck + koff);
            const f32x4 ck1 = *(const f32x4*)(ck + koff + 16);
            const f32x4 mk0 = *(const f32x4*)(mk + koff);
            const f32x4 mk1 = *(const f32x4*)(mk + koff + 16);

            // scores in log2 domain
            float s0[4], s1[4];
#pragma unroll
            for (int r = 0; r < 4; ++r) {
                s0[r] = st[0][r] * ck0[r] + mk0[r];
                s1[r] = st[1][r] * ck1[r] + mk1[r];
            }
            const float lmax =
                fmaxf(fmaxf(fmaxf(s0[0], s0[1]), fmaxf(s0[2], s0[3])),
                      fmaxf(fmaxf(s1[0], s1[1]), fmaxf(s1[2], s1[3])));

            // defer-max: cross-lane reduce + rescale only when needed
            // (threshold 8*log2e in log2 domain -> P bounded by e^8)
            if (__any(lmax - m_run > 11.5415603f)) {
                float tmax = lmax;
                tmax = fmaxf(tmax, __shfl_xor(tmax, 16));
                tmax = fmaxf(tmax, __shfl_xor(tmax, 32));
                const float m_new = fmaxf(m_run, tmax);
                const float sc = __builtin_amdgcn_exp2f(m_run - m_new);
                l_run *= sc;
#pragma unroll
                for (int f = 0; f < 4; ++f)
#pragma unroll
                    for (int r = 0; r < 4; ++r) o[f][r] *= sc;
                m_run = m_new;
            }

            float psum = 0.f;
            f16x4 pk0, pk1;
#pragma unroll
            for (int r = 0; r < 4; ++r) {
                const float p0 = __builtin_amdgcn_exp2f(s0[r] - m_run);
                const float p1 = __builtin_amdgcn_exp2f(s1[r] - m_run);
                psum += p0 + p1;
                pk0[r] = (_Float16)p0;
                pk1[r] = (_Float16)p1;
            }
            l_run += psum;       // per-lane partial; reduced in epilogue

            // --- P^T bounce (wave-private)
            *(f16x4*)(&pT[w][lr][lg * 4]) = pk0;
            *(f16x4*)(&pT[w][lr][16 + lg * 4]) = pk1;
            const f16x8 pb = *(const f16x8*)(&pT[w][lr][lg * 8]);

            // --- PV: o[f] += V^T tile (A) x P^T (B), V from LDS
            __builtin_amdgcn_s_setprio(1);
#pragma unroll
            for (int f = 0; f < 4; ++f) {
                const int vrow = f * 16 + lr;
                const f16x8 vf = *(const f16x8*)(Vs + vrow * 64 +
                                                 ((((ks << 6) | (lg << 4)) ^ sw) >> 1));
                o[f] = __builtin_amdgcn_mfma_f32_16x16x32_f16(vf, pb, o[f], 0, 0, 0);
            }
            __builtin_amdgcn_s_setprio(0);
        }
        __syncthreads();   // drain next-chunk staging + release buffers
    }

    // --- epilogue: cross-lane l_run reduction (once), normalize + store
    float lt = l_run;
    lt += __shfl_xor(lt, 16);
    lt += __shfl_xor(lt, 32);
    const float inv = 1.f / lt;
#pragma unroll
    for (int f = 0; f < 4; ++f) {
        f32x4 v = o[f];
#pragma unroll
        for (int r = 0; r < 4; ++r) v[r] *= inv;
        float* dst = out + ((size_t)(b_ * SS + qbase + lr)) * DD +
                     h * 64 + f * 16 + lg * 4;
        *(f32x4*)dst = v;
    }
}

// ---------------------------------------------------------------------------
// Launch
// ---------------------------------------------------------------------------
extern "C" void kernel_launch(void* const* d_in, const int* in_sizes, int n_in,
                              void* d_out, int out_size, void* d_ws, size_t ws_size,
                              hipStream_t stream) {
    const float* X     = (const float*)d_in[0];
    const float* mask  = (const float*)d_in[1];
    const float* click = (const float*)d_in[2];
    const float* Wq    = (const float*)d_in[3];
    const float* bq    = (const float*)d_in[4];
    const float* Wk    = (const float*)d_in[5];
    const float* bk    = (const float*)d_in[6];
    const float* Wv    = (const float*)d_in[7];
    const float* bv    = (const float*)d_in[8];
    float* out = (float*)d_out;

    char* ws = (char*)d_ws;
    _Float16* Xh  = (_Float16*)(ws);                  // 12,582,912 B
    _Float16* Wh  = (_Float16*)(ws + 12582912);       //  3,538,944 B
    float*    bia = (float*)   (ws + 16121856);       //      9,216 B
    float*    ckS = (float*)   (ws + 16131072);       //     32,768 B
    float*    mkL = (float*)   (ws + 16163840);       //     32,768 B
    _Float16* Qb  = (_Float16*)(ws + 16196608);       // 12,582,912 B
    _Float16* Kb  = (_Float16*)(ws + 28779520);       // 12,582,912 B
    _Float16* Vt  = (_Float16*)(ws + 41362432);       // 12,582,912 B

    prep_kernel<<<2048, 256, 0, stream>>>(X, Wq, Wk, Wv, bq, bk, bv, click, mask,
                                          Xh, Wh, bia, ckS, mkL);
    qkv_gemm<<<768, 256, 0, stream>>>(Xh, Wh, bia, Qb, Kb, Vt);
    attn_kernel<<<768, 512, 0, stream>>>(Qb, Kb, Vt, ckS, mkL, out);
}